// Round 1
// baseline (79.384 us; speedup 1.0000x reference)
//
#include <hip/hip_runtime.h>
#include <math.h>

#define NPIX (8 * 256 * 256)   // B*H*W
#define CC 16                  // C
#define KK 8                   // K

// Precomputed per-class data: Linv[K][C][C] row-major, then logdet[K]
__device__ float g_pre[KK * CC * CC + KK];

// One column of each class's triangular inverse per thread (K*C = 128 threads).
__global__ void precompute_kernel(const float* __restrict__ st) {
    int t = threadIdx.x;
    if (t >= KK * CC) return;
    int k = t >> 4;
    int j = t & 15;
    const float* L = st + k * CC * CC;   // row-major [C][C]; use lower triangle only

    float col[CC];
    for (int i = 0; i < CC; ++i) {
        if (i < j) { col[i] = 0.0f; continue; }
        float s = (i == j) ? 1.0f : 0.0f;
        for (int m = j; m < i; ++m) s -= L[i * CC + m] * col[m];
        col[i] = s / L[i * CC + i];
    }
    for (int i = 0; i < CC; ++i) g_pre[k * CC * CC + i * CC + j] = col[i];

    if (j == 0) {
        float ld = 0.0f;
        for (int i = 0; i < CC; ++i) ld += logf(fabsf(L[i * CC + i]));
        g_pre[KK * CC * CC + k] = ld;
    }
}

__global__ __launch_bounds__(256) void mvn_kernel(const float* __restrict__ x,
                                                  const float* __restrict__ mean,
                                                  float* __restrict__ out) {
    const int p = blockIdx.x * 256 + threadIdx.x;   // pixel index, grid covers exactly

    // ---- load x[16] (64B aligned) ----
    const float4* xp = reinterpret_cast<const float4*>(x + (size_t)p * CC);
    float xv[CC];
#pragma unroll
    for (int q = 0; q < 4; ++q) {
        float4 v = xp[q];
        xv[4 * q + 0] = v.x; xv[4 * q + 1] = v.y;
        xv[4 * q + 2] = v.z; xv[4 * q + 3] = v.w;
    }

    const float HALF_C_LOG2PI = 14.703517f;  // 0.5 * 16 * log(2*pi)

    float pk[KK];
#pragma unroll
    for (int k = 0; k < KK; ++k) {
        float diff[CC];
#pragma unroll
        for (int c = 0; c < CC; ++c) diff[c] = xv[c] - mean[k * CC + c];

        float quad = 0.0f;
#pragma unroll
        for (int i = 0; i < CC; ++i) {
            float z = 0.0f;
#pragma unroll
            for (int j = 0; j <= i; ++j)
                z = fmaf(g_pre[k * CC * CC + i * CC + j], diff[j], z);
            quad = fmaf(z, z, quad);
        }
        float logp = -0.5f * quad - HALF_C_LOG2PI - g_pre[KK * CC * CC + k];
        pk[k] = __expf(logp);   // fp32 underflow semantics ~ match reference
    }

    float ss = 0.0f;
#pragma unroll
    for (int k = 0; k < KK; ++k) ss = fmaf(pk[k], pk[k], ss);
    float inv = rsqrtf(fmaxf(ss, 1e-12f));

    // ---- write out[24] (96B per pixel, 16B aligned) ----
    float o[24];
#pragma unroll
    for (int c = 0; c < CC; ++c) o[c] = xv[c];
#pragma unroll
    for (int k = 0; k < KK; ++k) o[CC + k] = pk[k] * inv;

    float4* op = reinterpret_cast<float4*>(out + (size_t)p * 24);
#pragma unroll
    for (int q = 0; q < 6; ++q)
        op[q] = make_float4(o[4 * q + 0], o[4 * q + 1], o[4 * q + 2], o[4 * q + 3]);
}

extern "C" void kernel_launch(void* const* d_in, const int* in_sizes, int n_in,
                              void* d_out, int out_size, void* d_ws, size_t ws_size,
                              hipStream_t stream) {
    const float* x    = (const float*)d_in[0];   // [B,H,W,C] fp32
    const float* mean = (const float*)d_in[1];   // [K,C] fp32
    const float* st   = (const float*)d_in[2];   // [K,C,C] fp32
    float* out = (float*)d_out;                  // [B,H,W,C+K] fp32

    precompute_kernel<<<1, 128, 0, stream>>>(st);
    mvn_kernel<<<NPIX / 256, 256, 0, stream>>>(x, mean, out);
}